// Round 1
// baseline (1244.102 us; speedup 1.0000x reference)
//
#include <hip/hip_runtime.h>

// Problem constants (shapes are fixed by the reference; N/K derived at launch).
constexpr int INC  = 32;
constexpr int OUTC = 32;

// ---------------------------------------------------------------------------
// Scatter conv: for each (k, n): out[out_idx[k][n]] += feats[in_idx[k][n]] @ W_k
// lane = output channel c (0..31). Each 32-lane half-wave processes one row.
// W_k column c lives in 32 VGPRs per lane (block is pinned to one k).
// Row broadcast: ds_swizzle BitMode (and=0, or=i) broadcasts lane i within
// each 32-lane group -> no LDS storage, no VALU address math.
// ---------------------------------------------------------------------------
__global__ __launch_bounds__(256) void scatter_conv_kernel(
    const float* __restrict__ feats,    // [N][32]
    const float* __restrict__ wkern,    // [K][32][32]
    const int*   __restrict__ in_idx,   // [K][N]
    const int*   __restrict__ out_idx,  // [K][N]
    float*       __restrict__ out,      // [N][32] accumulator (pre-zeroed)
    int N)
{
    const int k     = blockIdx.y;
    const int c     = threadIdx.x & 31;        // output channel
    const int group = (blockIdx.x << 3) + (threadIdx.x >> 5);  // 8 groups/block
    const int ngroups = gridDim.x << 3;

    // W_k[:, c] -> registers (coalesced: 32 consecutive floats per half-wave)
    float w[32];
    const float* wk = wkern + (size_t)k * (INC * OUTC) + c;
#pragma unroll
    for (int i = 0; i < 32; ++i) w[i] = wk[i * OUTC];

    const int* iin_p  = in_idx  + (size_t)k * N;
    const int* iout_p = out_idx + (size_t)k * N;

    for (int n = group; n < N; n += ngroups) {
        const int iin  = iin_p[n];    // same addr across 32 lanes -> broadcast
        const int iout = iout_p[n];

        // lane c loads its element of the gathered row (coalesced 128B/row)
        const float f  = feats[(size_t)iin * INC + c];
        const int   fi = __float_as_int(f);

        float acc = 0.0f;
        // acc = sum_i row[i] * W_k[i][c]; row[i] via swizzle-broadcast of lane i
#define STEP(i) { float b = __int_as_float(__builtin_amdgcn_ds_swizzle(fi, ((i) << 5))); acc = fmaf(b, w[i], acc); }
        STEP(0)  STEP(1)  STEP(2)  STEP(3)  STEP(4)  STEP(5)  STEP(6)  STEP(7)
        STEP(8)  STEP(9)  STEP(10) STEP(11) STEP(12) STEP(13) STEP(14) STEP(15)
        STEP(16) STEP(17) STEP(18) STEP(19) STEP(20) STEP(21) STEP(22) STEP(23)
        STEP(24) STEP(25) STEP(26) STEP(27) STEP(28) STEP(29) STEP(30) STEP(31)
#undef STEP

        // contiguous 128B atomic segment per row (32 lanes x 4B)
        unsafeAtomicAdd(out + (size_t)iout * OUTC + c, acc);
    }
}

// ---------------------------------------------------------------------------
// In-place BN (eval) + ReLU over [N][32]. float4 vectorized; channel block of
// a thread is invariant across the grid-stride loop (stride % 8 == 0).
// ---------------------------------------------------------------------------
__global__ __launch_bounds__(256) void bn_relu_kernel(
    float* __restrict__ out,
    const float* __restrict__ gamma,
    const float* __restrict__ beta,
    const float* __restrict__ mean,
    const float* __restrict__ var,
    int total4)
{
    const int tid    = blockIdx.x * blockDim.x + threadIdx.x;
    const int stride = gridDim.x * blockDim.x;
    const int c0     = (tid & 7) << 2;   // first of 4 channels this thread owns

    float s[4], b[4];
#pragma unroll
    for (int j = 0; j < 4; ++j) {
        const int c = c0 + j;
        s[j] = gamma[c] * rsqrtf(var[c] + 1e-5f);
        b[j] = beta[c] - mean[c] * s[j];
    }

    float4* p = (float4*)out;
    for (int i = tid; i < total4; i += stride) {
        float4 v = p[i];
        v.x = fmaxf(fmaf(v.x, s[0], b[0]), 0.0f);
        v.y = fmaxf(fmaf(v.y, s[1], b[1]), 0.0f);
        v.z = fmaxf(fmaf(v.z, s[2], b[2]), 0.0f);
        v.w = fmaxf(fmaf(v.w, s[3], b[3]), 0.0f);
        p[i] = v;
    }
}

extern "C" void kernel_launch(void* const* d_in, const int* in_sizes, int n_in,
                              void* d_out, int out_size, void* d_ws, size_t ws_size,
                              hipStream_t stream) {
    const float* feats   = (const float*)d_in[0];
    const float* wkern   = (const float*)d_in[1];
    const float* gamma   = (const float*)d_in[2];
    const float* beta    = (const float*)d_in[3];
    const float* mean    = (const float*)d_in[4];
    const float* var     = (const float*)d_in[5];
    const int*   in_idx  = (const int*)d_in[6];
    const int*   out_idx = (const int*)d_in[7];
    float*       out     = (float*)d_out;

    const int N = in_sizes[0] / INC;                  // 400000
    const int K = in_sizes[1] / (INC * OUTC);         // 27

    // Zero the accumulator (d_out is poisoned to 0xAA before every launch).
    hipMemsetAsync(out, 0, (size_t)out_size * sizeof(float), stream);

    // 150 blocks/k * 8 groups = 1200 groups/k -> ~334 rows per group.
    dim3 grid(150, K);
    scatter_conv_kernel<<<grid, 256, 0, stream>>>(feats, wkern, in_idx, out_idx, out, N);

    const int total4 = out_size / 4;
    bn_relu_kernel<<<1024, 256, 0, stream>>>(out, gamma, beta, mean, var, total4);
}

// Round 2
// 1219.083 us; speedup vs baseline: 1.0205x; 1.0205x over previous
//
#include <hip/hip_runtime.h>
#include <hip/hip_bf16.h>

constexpr int INC  = 32;
constexpr int OUTC = 32;

typedef __bf16 bf16x8 __attribute__((ext_vector_type(8)));
typedef float  f32x4  __attribute__((ext_vector_type(4)));

// ---------------------------------------------------------------------------
// MFMA scatter conv. One wave processes a 16-row tile per iteration:
//   A-frag  : 16 gathered feats rows as bf16  (A[m=lane&15][k=quad*8+j])
//   B-frags : W_k columns 0..15 / 16..31     (B[k=quad*8+j][n=lane&15])
//   D       : 16x16 fp32 tiles (col=lane&15, row=quad*4+reg) -> scatter atomics
// No LDS at all (R1 was LDS-swizzle-pipe bound at ~4cyc x 675K/CU).
// ---------------------------------------------------------------------------
__global__ __launch_bounds__(256) void scatter_conv_mfma(
    const float* __restrict__ feats,    // [N][32]
    const float* __restrict__ wkern,    // [K][32][32]
    const int*   __restrict__ in_idx,   // [K][N]
    const int*   __restrict__ out_idx,  // [K][N]
    float*       __restrict__ out,      // [N][32] accumulator (pre-zeroed)
    int N)
{
    const int k    = blockIdx.y;
    const int lane = threadIdx.x & 63;
    const int col  = lane & 15;   // A row m / D col n
    const int quad = lane >> 4;

    const int wave   = blockIdx.x * 4 + (threadIdx.x >> 6);
    const int nwaves = gridDim.x * 4;

    // B fragments for this k-offset (loaded once; strided but negligible).
    const float* wk = wkern + (size_t)k * (INC * OUTC);
    bf16x8 b0, b1;
#pragma unroll
    for (int j = 0; j < 8; ++j) {
        const int kk = quad * 8 + j;
        b0[j] = (__bf16)wk[kk * OUTC + col];
        b1[j] = (__bf16)wk[kk * OUTC + 16 + col];
    }

    const int* iin_p  = in_idx  + (size_t)k * N;
    const int* iout_p = out_idx + (size_t)k * N;
    const int  ntiles = N >> 4;          // N % 16 == 0 (400000/16 = 25000)

    for (int t = wave; t < ntiles; t += nwaves) {
        const int base = t << 4;

        // Row index for this lane's A row (16 distinct, broadcast x4 quads).
        const int iin = iin_p[base + col];

        // Scatter targets for this lane's 4 D rows (quad*4 + r).
        int orow[4];
#pragma unroll
        for (int r = 0; r < 4; ++r) orow[r] = iout_p[base + quad * 4 + r];

        // Gather A: 32B contiguous per lane = feats[iin][quad*8 .. quad*8+8)
        const float4* ap = (const float4*)(feats + (size_t)iin * INC + quad * 8);
        const float4 a_lo = ap[0];
        const float4 a_hi = ap[1];
        bf16x8 a;
        a[0] = (__bf16)a_lo.x; a[1] = (__bf16)a_lo.y;
        a[2] = (__bf16)a_lo.z; a[3] = (__bf16)a_lo.w;
        a[4] = (__bf16)a_hi.x; a[5] = (__bf16)a_hi.y;
        a[6] = (__bf16)a_hi.z; a[7] = (__bf16)a_hi.w;

        f32x4 acc0 = {0.f, 0.f, 0.f, 0.f};
        f32x4 acc1 = {0.f, 0.f, 0.f, 0.f};
        acc0 = __builtin_amdgcn_mfma_f32_16x16x32_bf16(a, b0, acc0, 0, 0, 0);
        acc1 = __builtin_amdgcn_mfma_f32_16x16x32_bf16(a, b1, acc1, 0, 0, 0);

        // Scatter-add: per r, one atomic instr covers 4 distinct out rows x 64B.
#pragma unroll
        for (int r = 0; r < 4; ++r) {
            float* dst = out + (size_t)orow[r] * OUTC + col;
            unsafeAtomicAdd(dst,      acc0[r]);
            unsafeAtomicAdd(dst + 16, acc1[r]);
        }
    }
}

// ---------------------------------------------------------------------------
// In-place BN (eval) + ReLU over [N][32]. float4 vectorized.
// ---------------------------------------------------------------------------
__global__ __launch_bounds__(256) void bn_relu_kernel(
    float* __restrict__ out,
    const float* __restrict__ gamma,
    const float* __restrict__ beta,
    const float* __restrict__ mean,
    const float* __restrict__ var,
    int total4)
{
    const int tid    = blockIdx.x * blockDim.x + threadIdx.x;
    const int stride = gridDim.x * blockDim.x;
    const int c0     = (tid & 7) << 2;

    float s[4], b[4];
#pragma unroll
    for (int j = 0; j < 4; ++j) {
        const int c = c0 + j;
        s[j] = gamma[c] * rsqrtf(var[c] + 1e-5f);
        b[j] = beta[c] - mean[c] * s[j];
    }

    float4* p = (float4*)out;
    for (int i = tid; i < total4; i += stride) {
        float4 v = p[i];
        v.x = fmaxf(fmaf(v.x, s[0], b[0]), 0.0f);
        v.y = fmaxf(fmaf(v.y, s[1], b[1]), 0.0f);
        v.z = fmaxf(fmaf(v.z, s[2], b[2]), 0.0f);
        v.w = fmaxf(fmaf(v.w, s[3], b[3]), 0.0f);
        p[i] = v;
    }
}

extern "C" void kernel_launch(void* const* d_in, const int* in_sizes, int n_in,
                              void* d_out, int out_size, void* d_ws, size_t ws_size,
                              hipStream_t stream) {
    const float* feats   = (const float*)d_in[0];
    const float* wkern   = (const float*)d_in[1];
    const float* gamma   = (const float*)d_in[2];
    const float* beta    = (const float*)d_in[3];
    const float* mean    = (const float*)d_in[4];
    const float* var     = (const float*)d_in[5];
    const int*   in_idx  = (const int*)d_in[6];
    const int*   out_idx = (const int*)d_in[7];
    float*       out     = (float*)d_out;

    const int N = in_sizes[0] / INC;                  // 400000
    const int K = in_sizes[1] / (INC * OUTC);         // 27

    // Zero the accumulator (d_out is poisoned to 0xAA before every launch).
    hipMemsetAsync(out, 0, (size_t)out_size * sizeof(float), stream);

    // 80 blocks x 4 waves = 320 waves per k-plane; 25000 tiles -> ~78 iters/wave.
    // 80*27 = 2160 blocks = 8640 waves vs 8192-wave device capacity.
    dim3 grid(80, K);
    scatter_conv_mfma<<<grid, 256, 0, stream>>>(feats, wkern, in_idx, out_idx, out, N);

    const int total4 = out_size / 4;
    bn_relu_kernel<<<1024, 256, 0, stream>>>(out, gamma, beta, mean, var, total4);
}

// Round 3
// 691.033 us; speedup vs baseline: 1.8004x; 1.7641x over previous
//
#include <hip/hip_runtime.h>
#include <hip/hip_bf16.h>
#include <hip/hip_fp16.h>

constexpr int INC  = 32;
constexpr int OUTC = 32;

typedef __bf16 bf16x8 __attribute__((ext_vector_type(8)));
typedef float  f32x4  __attribute__((ext_vector_type(4)));

// ---------------------------------------------------------------------------
// MFMA scatter conv, packed-fp16 atomics. One wave = 16-row tile:
//   A-frag : 16 gathered feats rows as bf16 (A[m=lane&15][k=quad*8+j])
//   B-frag : column-permuted so acc0 -> out-ch 2c, acc1 -> out-ch 2c+1
//            (c = lane&15)  ==> each lane packs its own __half2, no shuffles.
//   Scatter: 4 pk_add_f16 atomics per lane (vs 8 fp32) -> halves the
//            atomic-op count, which R1/R2 showed is the wall (~319 G/s).
// ---------------------------------------------------------------------------
__global__ __launch_bounds__(256) void scatter_conv_mfma_pk(
    const float* __restrict__ feats,    // [N][32]
    const float* __restrict__ wkern,    // [K][32][32]
    const int*   __restrict__ in_idx,   // [K][N]
    const int*   __restrict__ out_idx,  // [K][N]
    __half2*     __restrict__ ws,       // [N][16] half2 accumulator (zeroed)
    int N)
{
    const int k    = blockIdx.y;
    const int lane = threadIdx.x & 63;
    const int col  = lane & 15;
    const int quad = lane >> 4;

    const int wave   = blockIdx.x * 4 + (threadIdx.x >> 6);
    const int nwaves = gridDim.x * 4;

    // B fragments, column-permuted: b0 -> channel 2*col, b1 -> channel 2*col+1
    const float* wk = wkern + (size_t)k * (INC * OUTC);
    bf16x8 b0, b1;
#pragma unroll
    for (int j = 0; j < 8; ++j) {
        const int kk = quad * 8 + j;
        b0[j] = (__bf16)wk[kk * OUTC + 2 * col];
        b1[j] = (__bf16)wk[kk * OUTC + 2 * col + 1];
    }

    const int* iin_p  = in_idx  + (size_t)k * N;
    const int* iout_p = out_idx + (size_t)k * N;
    const int  ntiles = N >> 4;

    for (int t = wave; t < ntiles; t += nwaves) {
        const int base = t << 4;

        const int iin = iin_p[base + col];          // A-row index for lane's m
        int orow[4];
#pragma unroll
        for (int r = 0; r < 4; ++r) orow[r] = iout_p[base + quad * 4 + r];

        const float4* ap = (const float4*)(feats + (size_t)iin * INC + quad * 8);
        const float4 a_lo = ap[0];
        const float4 a_hi = ap[1];
        bf16x8 a;
        a[0] = (__bf16)a_lo.x; a[1] = (__bf16)a_lo.y;
        a[2] = (__bf16)a_lo.z; a[3] = (__bf16)a_lo.w;
        a[4] = (__bf16)a_hi.x; a[5] = (__bf16)a_hi.y;
        a[6] = (__bf16)a_hi.z; a[7] = (__bf16)a_hi.w;

        f32x4 acc0 = {0.f, 0.f, 0.f, 0.f};
        f32x4 acc1 = {0.f, 0.f, 0.f, 0.f};
        acc0 = __builtin_amdgcn_mfma_f32_16x16x32_bf16(a, b0, acc0, 0, 0, 0);
        acc1 = __builtin_amdgcn_mfma_f32_16x16x32_bf16(a, b1, acc1, 0, 0, 0);

        // D row = quad*4+r; lane covers channels (2c, 2c+1) -> one pk atomic.
#pragma unroll
        for (int r = 0; r < 4; ++r) {
            __half2 v = __halves2half2(__float2half(acc0[r]), __float2half(acc1[r]));
            unsafeAtomicAdd(ws + (size_t)orow[r] * 16 + col, v);
        }
    }
}

// BN+ReLU: fp16 accumulator in -> fp32 out. One half2 (2 channels) per thread.
__global__ __launch_bounds__(256) void bn_relu_f16(
    const __half2* __restrict__ ws,
    float* __restrict__ out,
    const float* __restrict__ gamma,
    const float* __restrict__ beta,
    const float* __restrict__ mean,
    const float* __restrict__ var,
    int total2)   // N*16
{
    const int tid    = blockIdx.x * blockDim.x + threadIdx.x;
    const int stride = gridDim.x * blockDim.x;
    const int p      = tid & 15;            // half2 index within row
    const int c0     = 2 * p;

    float s0 = gamma[c0]     * rsqrtf(var[c0]     + 1e-5f);
    float s1 = gamma[c0 + 1] * rsqrtf(var[c0 + 1] + 1e-5f);
    float q0 = beta[c0]     - mean[c0]     * s0;
    float q1 = beta[c0 + 1] - mean[c0 + 1] * s1;

    float2* po = (float2*)out;
    for (int i = tid; i < total2; i += stride) {
        const __half2 h = ws[i];
        float2 v;
        v.x = fmaxf(fmaf(__low2float(h),  s0, q0), 0.0f);
        v.y = fmaxf(fmaf(__high2float(h), s1, q1), 0.0f);
        po[i] = v;
    }
}

// ------------------------- fp32 fallback (R2 path) -------------------------
__global__ __launch_bounds__(256) void scatter_conv_mfma_f32(
    const float* __restrict__ feats,
    const float* __restrict__ wkern,
    const int*   __restrict__ in_idx,
    const int*   __restrict__ out_idx,
    float*       __restrict__ out,
    int N)
{
    const int k    = blockIdx.y;
    const int lane = threadIdx.x & 63;
    const int col  = lane & 15;
    const int quad = lane >> 4;
    const int wave   = blockIdx.x * 4 + (threadIdx.x >> 6);
    const int nwaves = gridDim.x * 4;

    const float* wk = wkern + (size_t)k * (INC * OUTC);
    bf16x8 b0, b1;
#pragma unroll
    for (int j = 0; j < 8; ++j) {
        const int kk = quad * 8 + j;
        b0[j] = (__bf16)wk[kk * OUTC + col];
        b1[j] = (__bf16)wk[kk * OUTC + 16 + col];
    }

    const int* iin_p  = in_idx  + (size_t)k * N;
    const int* iout_p = out_idx + (size_t)k * N;
    const int  ntiles = N >> 4;

    for (int t = wave; t < ntiles; t += nwaves) {
        const int base = t << 4;
        const int iin = iin_p[base + col];
        int orow[4];
#pragma unroll
        for (int r = 0; r < 4; ++r) orow[r] = iout_p[base + quad * 4 + r];

        const float4* ap = (const float4*)(feats + (size_t)iin * INC + quad * 8);
        const float4 a_lo = ap[0];
        const float4 a_hi = ap[1];
        bf16x8 a;
        a[0] = (__bf16)a_lo.x; a[1] = (__bf16)a_lo.y;
        a[2] = (__bf16)a_lo.z; a[3] = (__bf16)a_lo.w;
        a[4] = (__bf16)a_hi.x; a[5] = (__bf16)a_hi.y;
        a[6] = (__bf16)a_hi.z; a[7] = (__bf16)a_hi.w;

        f32x4 acc0 = {0.f, 0.f, 0.f, 0.f};
        f32x4 acc1 = {0.f, 0.f, 0.f, 0.f};
        acc0 = __builtin_amdgcn_mfma_f32_16x16x32_bf16(a, b0, acc0, 0, 0, 0);
        acc1 = __builtin_amdgcn_mfma_f32_16x16x32_bf16(a, b1, acc1, 0, 0, 0);

#pragma unroll
        for (int r = 0; r < 4; ++r) {
            float* dst = out + (size_t)orow[r] * OUTC + col;
            unsafeAtomicAdd(dst,      acc0[r]);
            unsafeAtomicAdd(dst + 16, acc1[r]);
        }
    }
}

__global__ __launch_bounds__(256) void bn_relu_f32_inplace(
    float* __restrict__ out,
    const float* __restrict__ gamma,
    const float* __restrict__ beta,
    const float* __restrict__ mean,
    const float* __restrict__ var,
    int total4)
{
    const int tid    = blockIdx.x * blockDim.x + threadIdx.x;
    const int stride = gridDim.x * blockDim.x;
    const int c0     = (tid & 7) << 2;

    float s[4], b[4];
#pragma unroll
    for (int j = 0; j < 4; ++j) {
        const int c = c0 + j;
        s[j] = gamma[c] * rsqrtf(var[c] + 1e-5f);
        b[j] = beta[c] - mean[c] * s[j];
    }

    float4* p = (float4*)out;
    for (int i = tid; i < total4; i += stride) {
        float4 v = p[i];
        v.x = fmaxf(fmaf(v.x, s[0], b[0]), 0.0f);
        v.y = fmaxf(fmaf(v.y, s[1], b[1]), 0.0f);
        v.z = fmaxf(fmaf(v.z, s[2], b[2]), 0.0f);
        v.w = fmaxf(fmaf(v.w, s[3], b[3]), 0.0f);
        p[i] = v;
    }
}

extern "C" void kernel_launch(void* const* d_in, const int* in_sizes, int n_in,
                              void* d_out, int out_size, void* d_ws, size_t ws_size,
                              hipStream_t stream) {
    const float* feats   = (const float*)d_in[0];
    const float* wkern   = (const float*)d_in[1];
    const float* gamma   = (const float*)d_in[2];
    const float* beta    = (const float*)d_in[3];
    const float* mean    = (const float*)d_in[4];
    const float* var     = (const float*)d_in[5];
    const int*   in_idx  = (const int*)d_in[6];
    const int*   out_idx = (const int*)d_in[7];
    float*       out     = (float*)d_out;

    const int N = in_sizes[0] / INC;                  // 400000
    const int K = in_sizes[1] / (INC * OUTC);         // 27

    const size_t need = (size_t)N * OUTC * sizeof(__half);  // 25.6 MB
    dim3 grid(80, K);

    if (ws_size >= need) {
        __half2* acc = (__half2*)d_ws;
        hipMemsetAsync(acc, 0, need, stream);
        scatter_conv_mfma_pk<<<grid, 256, 0, stream>>>(feats, wkern, in_idx, out_idx, acc, N);
        bn_relu_f16<<<1024, 256, 0, stream>>>(acc, out, gamma, beta, mean, var, N * 16);
    } else {
        hipMemsetAsync(out, 0, (size_t)out_size * sizeof(float), stream);
        scatter_conv_mfma_f32<<<grid, 256, 0, stream>>>(feats, wkern, in_idx, out_idx, out, N);
        bn_relu_f32_inplace<<<1024, 256, 0, stream>>>(out, gamma, beta, mean, var, out_size / 4);
    }
}